// Round 6
// baseline (195.789 us; speedup 1.0000x reference)
//
#include <hip/hip_runtime.h>
#include <hip/hip_bf16.h>

typedef __attribute__((ext_vector_type(8))) short bf16x8;
typedef __attribute__((ext_vector_type(4))) float f32x4;

#define NN 4096
#define DD 64
#define LL 16
// sqrt(log2(e)): prescaling x by this makes dot = log2(e)*<x,x'>, so
// K = exp(dot - hi - hj) becomes exp2(g - hi - hj) with g straight from MFMA.
#define SCALE 1.2011224087864498f
// skip threshold (base-2 exponent): skipped terms <= 2^-24 each.
#define THR -24.0f

#define BUF_BYTES 8448
#define H_OFF 8192
#define NBUF 4

__device__ __forceinline__ ushort f2bf(float f) {
    unsigned int u = __float_as_uint(f);
    unsigned int r = u + 0x7FFFu + ((u >> 16) & 1u);
    return (ushort)(r >> 16);
}
__device__ __forceinline__ float bf2f(ushort u) {
    return __uint_as_float(((unsigned int)u) << 16);
}

__device__ __forceinline__ void gload_lds16(const void* g, void* l) {
    __builtin_amdgcn_global_load_lds((const __attribute__((address_space(1))) unsigned int*)g,
                                     (__attribute__((address_space(3))) unsigned int*)l, 16, 0, 0);
}
__device__ __forceinline__ void gload_lds4(const void* g, void* l) {
    __builtin_amdgcn_global_load_lds((const __attribute__((address_space(1))) unsigned int*)g,
                                     (__attribute__((address_space(3))) unsigned int*)l, 4, 0, 0);
}

// Transpose (N,D,L) fp32 -> (L,N,D) bf16 with per-row 16B-chunk XOR swizzle
// (chunk co of row n stored at co ^ (n&7)), values prescaled by SCALE, and
// h[l][n] = 0.5 * sum_d xs_bf16^2 (fp32, from the SAME bf16 values MFMA sees).
__global__ void prep_kernel(const float* __restrict__ X, const float* __restrict__ Y,
                            ushort* __restrict__ Xb, ushort* __restrict__ Yb,
                            float* __restrict__ hx, float* __restrict__ hy) {
    const float* in = blockIdx.y ? Y : X;
    ushort* outb    = blockIdx.y ? Yb : Xb;
    float* h        = blockIdx.y ? hy : hx;

    __shared__ float lds[64 * 17];
    __shared__ float psum[16][17];

    int n = blockIdx.x;
    int t = threadIdx.x;
    const float* row = in + (size_t)n * (DD * LL);

#pragma unroll
    for (int r = 0; r < 4; ++r) {
        int e = t + r * 256;        // e = d*16 + l
        lds[(e >> 4) * 17 + (e & 15)] = row[e];
    }
    __syncthreads();

    int l = t >> 4, c = t & 15;
    float p = 0.f;
    ushort4 w;
    {
        float v0 = lds[(c * 4 + 0) * 17 + l] * SCALE;
        float v1 = lds[(c * 4 + 1) * 17 + l] * SCALE;
        float v2 = lds[(c * 4 + 2) * 17 + l] * SCALE;
        float v3 = lds[(c * 4 + 3) * 17 + l] * SCALE;
        ushort u0 = f2bf(v0), u1 = f2bf(v1), u2 = f2bf(v2), u3 = f2bf(v3);
        float b0 = bf2f(u0), b1 = bf2f(u1), b2 = bf2f(u2), b3 = bf2f(u3);
        p = b0 * b0 + b1 * b1 + b2 * b2 + b3 * b3;
        w.x = u0; w.y = u1; w.z = u2; w.w = u3;
    }
    int cs = (c >> 1) ^ (n & 7);
    *reinterpret_cast<ushort4*>(outb + ((size_t)l * NN + n) * DD + cs * 8 + (c & 1) * 4) = w;

    psum[l][c] = p;
    __syncthreads();
    if (t < 16) {
        float s = 0.f;
#pragma unroll
        for (int i = 0; i < 16; ++i) s += psum[t][i];
        h[t * NN + n] = 0.5f * s;
    }
}

// Triangular fused kernel, 256-row i-tiles, software-pipelined.
// Grid = 16 l x 8 pairs x 8 segs = 1024. Pair p owns i-tiles {p, 15-p};
// unit list (136 = 8 segs x 17) concatenates jt in [8ti,128) for both tiles.
// Band units (jt-8ti < 8): full diagonal 256x256 block, weight 1.
// Strict-upper: weight 2 for T1, col sums mirrored to rows.
__global__ __launch_bounds__(256, 2) void hsic_tri(
    const ushort* __restrict__ Xb, const ushort* __restrict__ Yb,
    const float* __restrict__ hx, const float* __restrict__ hy,
    float* __restrict__ a_raw, float* __restrict__ b_raw, float* __restrict__ t1) {

    int blk = blockIdx.x;                       // 1024
    int l = (blk & 7) * 2 + ((blk >> 3) & 1);   // XCD-pinned l pair
    int p = (blk >> 4) & 7;
    int seg = blk >> 7;                          // 0..7
    int c = 128 - 8 * p;                         // units in phase A (ti = p)
    int u0 = seg * 17, u1 = u0 + 17;

    int wave = threadIdx.x >> 6;
    int lane = threadIdx.x & 63;
    int lrow = lane & 15;
    int khi  = lane >> 4;

    const ushort* Xl = Xb + (size_t)l * (NN * DD);
    const ushort* Yl = Yb + (size_t)l * (NN * DD);
    const float* hxl = hx + l * NN;
    const float* hyl = hy + l * NN;

    __shared__ __align__(16) char smem[NBUF * BUF_BYTES];

    float t1_1 = 0.f, t1_2 = 0.f;
    const f32x4 fzero = {0.f, 0.f, 0.f, 0.f};

    // per-lane LDS byte offsets for B fragments (within one buffer)
    int offb[2][2];
#pragma unroll
    for (int cg = 0; cg < 2; ++cg)
#pragma unroll
        for (int kc = 0; kc < 2; ++kc)
            offb[cg][kc] = (cg * 16 + lrow) * 128 + (((kc * 4 + khi) ^ (lrow & 7)) * 16);

    auto run_phase = [&](int ti, int jt0, int cnt) {
        __syncthreads();                         // full drain between phases
        int ibase = ti * 256 + wave * 64;

        // A fragments + per-lane 4-row h-min thresholds (test-side only)
        bf16x8 ax[4][2], ay[4][2];
        float thr2x[4], thr2y[4];
        int crow[4];
#pragma unroll
        for (int rg = 0; rg < 4; ++rg) {
            int arow = ibase + rg * 16 + lrow;
#pragma unroll
            for (int kc = 0; kc < 2; ++kc) {
                int cs = (kc * 4 + khi) ^ (arow & 7);
                ax[rg][kc] = *reinterpret_cast<const bf16x8*>(Xl + (size_t)arow * DD + cs * 8);
                ay[rg][kc] = *reinterpret_cast<const bf16x8*>(Yl + (size_t)arow * DD + cs * 8);
            }
            crow[rg] = ibase + rg * 16 + khi * 4;
            f32x4 hv = *reinterpret_cast<const f32x4*>(hxl + crow[rg]);
            thr2x[rg] = THR + fminf(fminf(hv[0], hv[1]), fminf(hv[2], hv[3]));
            f32x4 hw = *reinterpret_cast<const f32x4*>(hyl + crow[rg]);
            thr2y[rg] = THR + fminf(fminf(hw[0], hw[1]), fminf(hw[2], hw[3]));
        }

        // hoisted staging pointers (advance per stage)
        const ushort* sp = ((wave < 2) ? Xl : Yl)
                         + (size_t)(jt0 * 32 + ((wave * 2) & 3) * 8 + (lane >> 3)) * DD
                         + (lane & 7) * 8;
        const float* sph = (lane < 32) ? (hxl + jt0 * 32 + lane) : (hyl + jt0 * 32 + (lane - 32));
        int dst0 = (wave * 2) * 1024;
        int sb = 0;                               // next stage index

        auto do_stage = [&]() {
            char* base = smem + (sb & 3) * BUF_BYTES;
            gload_lds16(sp, base + dst0);
            gload_lds16(sp + 8 * DD, base + dst0 + 1024);
            gload_lds4(sph, base + H_OFF);        // all waves duplicate-stage h (uniform vmcnt)
            sp += 32 * DD; sph += 32; ++sb;
        };

        // prologue: up to 3 stages in flight, then first fragment set
        int nst = cnt < 3 ? cnt : 3;
        for (int s = 0; s < nst; ++s) do_stage();
        if (nst == 3)      asm volatile("s_waitcnt vmcnt(6)" ::: "memory");
        else if (nst == 2) asm volatile("s_waitcnt vmcnt(3)" ::: "memory");
        else               asm volatile("s_waitcnt vmcnt(0)" ::: "memory");
        __builtin_amdgcn_s_barrier();

        bf16x8 bxA[2][2], byA[2][2], bxB[2][2], byB[2][2];
        float hxjA[2], hyjA[2], hxjB[2], hyjB[2];
        int bo = 0;                               // buffer byte offset of next tile to read

        auto read_set = [&](bf16x8 (&bx)[2][2], bf16x8 (&by)[2][2],
                            float (&hxj)[2], float (&hyj)[2]) {
            const char* bc = smem + bo;
#pragma unroll
            for (int cg = 0; cg < 2; ++cg) {
#pragma unroll
                for (int kc = 0; kc < 2; ++kc) {
                    bx[cg][kc] = *reinterpret_cast<const bf16x8*>(bc + offb[cg][kc]);
                    by[cg][kc] = *reinterpret_cast<const bf16x8*>(bc + 4096 + offb[cg][kc]);
                }
                hxj[cg] = *reinterpret_cast<const float*>(bc + H_OFF + (cg * 16 + lrow) * 4);
                hyj[cg] = *reinterpret_cast<const float*>(bc + H_OFF + 128 + (cg * 16 + lrow) * 4);
            }
            bo = (bo == (NBUF - 1) * BUF_BYTES) ? 0 : bo + BUF_BYTES;
        };

        auto compute = [&](bf16x8 (&bx)[2][2], bf16x8 (&by)[2][2],
                           float (&hxj)[2], float (&hyj)[2], int jt) {
            f32x4 gx[4][2], gy[4][2];
            __builtin_amdgcn_s_setprio(1);
#pragma unroll
            for (int rg = 0; rg < 4; ++rg)
#pragma unroll
                for (int cg = 0; cg < 2; ++cg) {
                    f32x4 t0 = __builtin_amdgcn_mfma_f32_16x16x32_bf16(ax[rg][0], bx[cg][0], fzero, 0, 0, 0);
                    gx[rg][cg] = __builtin_amdgcn_mfma_f32_16x16x32_bf16(ax[rg][1], bx[cg][1], t0, 0, 0, 0);
                    f32x4 t1v = __builtin_amdgcn_mfma_f32_16x16x32_bf16(ay[rg][0], by[cg][0], fzero, 0, 0, 0);
                    gy[rg][cg] = __builtin_amdgcn_mfma_f32_16x16x32_bf16(ay[rg][1], by[cg][1], t1v, 0, 0, 0);
                }
            __builtin_amdgcn_s_setprio(0);

            // wave-uniform skip test: max4(g) - (THR + hmin_rg + hj) >= 0 anywhere?
            float dm = -1e30f;
#pragma unroll
            for (int rg = 0; rg < 4; ++rg)
#pragma unroll
                for (int cg = 0; cg < 2; ++cg) {
                    float mx = fmaxf(fmaxf(gx[rg][cg][0], gx[rg][cg][1]), fmaxf(gx[rg][cg][2], gx[rg][cg][3]));
                    float my = fmaxf(fmaxf(gy[rg][cg][0], gy[rg][cg][1]), fmaxf(gy[rg][cg][2], gy[rg][cg][3]));
                    dm = fmaxf(dm, mx - (thr2x[rg] + hxj[cg]));
                    dm = fmaxf(dm, my - (thr2y[rg] + hyj[cg]));
                }

            if (__ballot(dm >= 0.f)) {
                bool band = (jt - 8 * ti) < 8;
                int jb = jt * 32;
                f32x4 hvx[4], hvy[4];
#pragma unroll
                for (int rg = 0; rg < 4; ++rg) {
                    hvx[rg] = *reinterpret_cast<const f32x4*>(hxl + crow[rg]);
                    hvy[rg] = *reinterpret_cast<const f32x4*>(hyl + crow[rg]);
                }
                float colx[2] = {0.f, 0.f}, coly[2] = {0.f, 0.f};
#pragma unroll
                for (int rg = 0; rg < 4; ++rg)
#pragma unroll
                    for (int q = 0; q < 4; ++q) {
                        float kx0 = __builtin_exp2f(gx[rg][0][q] - hvx[rg][q] - hxj[0]);
                        float kx1 = __builtin_exp2f(gx[rg][1][q] - hvx[rg][q] - hxj[1]);
                        float ky0 = __builtin_exp2f(gy[rg][0][q] - hvy[rg][q] - hyj[0]);
                        float ky1 = __builtin_exp2f(gy[rg][1][q] - hvy[rg][q] - hyj[1]);
                        float pr = kx0 * ky0 + kx1 * ky1;
                        if (band) t1_1 += pr; else t1_2 += pr;
                        if (!band) { colx[0] += kx0; colx[1] += kx1; coly[0] += ky0; coly[1] += ky1; }
                        float rx = kx0 + kx1, ry = ky0 + ky1;
                        rx += __shfl_xor(rx, 1); rx += __shfl_xor(rx, 2);
                        rx += __shfl_xor(rx, 4); rx += __shfl_xor(rx, 8);
                        ry += __shfl_xor(ry, 1); ry += __shfl_xor(ry, 2);
                        ry += __shfl_xor(ry, 4); ry += __shfl_xor(ry, 8);
                        if (lrow == 0) {
                            atomicAdd(&a_raw[l * NN + crow[rg] + q], rx);
                            atomicAdd(&b_raw[l * NN + crow[rg] + q], ry);
                        }
                    }
                if (!band) {
#pragma unroll
                    for (int cg = 0; cg < 2; ++cg) {
                        float vx = colx[cg], vy = coly[cg];
                        vx += __shfl_xor(vx, 16); vx += __shfl_xor(vx, 32);
                        vy += __shfl_xor(vy, 16); vy += __shfl_xor(vy, 32);
                        if (khi == 0) {
                            atomicAdd(&a_raw[l * NN + jb + cg * 16 + lrow], vx);
                            atomicAdd(&b_raw[l * NN + jb + cg * 16 + lrow], vy);
                        }
                    }
                }
            }
        };

        read_set(bxA, byA, hxjA, hyjA);           // tile jt0 (buffer 0)

        auto iter_head = [&](int m) {
            if (m + 2 <= cnt - 1) asm volatile("s_waitcnt vmcnt(3)" ::: "memory");
            else                  asm volatile("s_waitcnt vmcnt(0)" ::: "memory");
            __builtin_amdgcn_s_barrier();
            if (m + 3 <= cnt - 1) do_stage();
        };

        int m = 0;
        while (true) {
            if (m == cnt - 1) {
                asm volatile("s_waitcnt lgkmcnt(0)" ::: "memory");
                __builtin_amdgcn_sched_barrier(0);
                compute(bxA, byA, hxjA, hyjA, jt0 + m);
                break;
            }
            iter_head(m);
            read_set(bxB, byB, hxjB, hyjB);
            asm volatile("s_waitcnt lgkmcnt(10)" ::: "memory");
            __builtin_amdgcn_sched_barrier(0);
            compute(bxA, byA, hxjA, hyjA, jt0 + m);
            ++m;
            if (m == cnt - 1) {
                asm volatile("s_waitcnt lgkmcnt(0)" ::: "memory");
                __builtin_amdgcn_sched_barrier(0);
                compute(bxB, byB, hxjB, hyjB, jt0 + m);
                break;
            }
            iter_head(m);
            read_set(bxA, byA, hxjA, hyjA);
            asm volatile("s_waitcnt lgkmcnt(10)" ::: "memory");
            __builtin_amdgcn_sched_barrier(0);
            compute(bxB, byB, hxjB, hyjB, jt0 + m);
            ++m;
        }
    };

    // phase A: ti = p, units [u0, min(u1,c)), jt = 8p + u
    int a_lo = u0, a_hi = (u1 < c) ? u1 : c;
    if (a_lo < a_hi) run_phase(p, 8 * p + a_lo, a_hi - a_lo);

    // phase B: ti = 15-p, units [max(u0,c), u1), jt = 8(15-p) + (u - c)
    int b_lo = (u0 > c) ? u0 : c, b_hi = u1;
    if (b_lo < b_hi) run_phase(15 - p, 8 * (15 - p) + (b_lo - c), b_hi - b_lo);

    float v = t1_1 + 2.f * t1_2;
#pragma unroll
    for (int sh = 1; sh < 64; sh <<= 1) v += __shfl_xor(v, sh);
    if (lane == 0) atomicAdd(&t1[l], v);
}

// One block per l; S_l = T1 - (2/n) sum A_i B_i + (sum A)(sum B)/n^2; atomicAdd into out.
__global__ void finalize_kernel(const float* __restrict__ a_raw, const float* __restrict__ b_raw,
                                const float* __restrict__ t1, float* __restrict__ out) {
    int l = blockIdx.x;
    int t = threadIdx.x;
    int lane = t & 63, w = t >> 6;

    float sab = 0.f, sa = 0.f, sb = 0.f;
    for (int i = t; i < NN; i += 256) {
        float av = a_raw[l * NN + i], bv = b_raw[l * NN + i];
        sab = __builtin_fmaf(av, bv, sab);
        sa += av;
        sb += bv;
    }
#pragma unroll
    for (int s = 1; s < 64; s <<= 1) {
        sab += __shfl_xor(sab, s);
        sa  += __shfl_xor(sa, s);
        sb  += __shfl_xor(sb, s);
    }
    __shared__ float sh[3][4];
    if (lane == 0) { sh[0][w] = sab; sh[1][w] = sa; sh[2][w] = sb; }
    __syncthreads();
    if (t == 0) {
        float rab = sh[0][0] + sh[0][1] + sh[0][2] + sh[0][3];
        float ra  = sh[1][0] + sh[1][1] + sh[1][2] + sh[1][3];
        float rb  = sh[2][0] + sh[2][1] + sh[2][2] + sh[2][3];
        const float n = (float)NN;
        float S = t1[l] - (2.f / n) * rab + (ra * rb) / (n * n);
        atomicAdd(out, S / (4095.f * 4095.f));
    }
}

extern "C" void kernel_launch(void* const* d_in, const int* in_sizes, int n_in,
                              void* d_out, int out_size, void* d_ws, size_t ws_size,
                              hipStream_t stream) {
    const float* X = (const float*)d_in[0];
    const float* Y = (const float*)d_in[1];
    float* out = (float*)d_out;
    char* ws = (char*)d_ws;

    const size_t XB_OFF  = 0;                       // L*N*D bf16 = 8388608 B
    const size_t YB_OFF  = 8388608;
    const size_t HX_OFF  = 16777216;                // L*N fp32
    const size_t HY_OFF  = 17039360;
    const size_t A_OFF   = 17301504;                // L*N fp32
    const size_t B_OFF   = 17563648;
    const size_t T1_OFF  = 17825792;                // L fp32

    ushort* Xb  = (ushort*)(ws + XB_OFF);
    ushort* Yb  = (ushort*)(ws + YB_OFF);
    float* hx   = (float*)(ws + HX_OFF);
    float* hy   = (float*)(ws + HY_OFF);
    float* a_raw = (float*)(ws + A_OFF);
    float* b_raw = (float*)(ws + B_OFF);
    float* t1    = (float*)(ws + T1_OFF);

    hipMemsetAsync(ws + A_OFF, 0, 2 * 262144 + 64, stream);
    hipMemsetAsync(d_out, 0, sizeof(float), stream);

    prep_kernel<<<dim3(NN, 2), 256, 0, stream>>>(X, Y, Xb, Yb, hx, hy);
    hsic_tri<<<1024, 256, 0, stream>>>(Xb, Yb, hx, hy, a_raw, b_raw, t1);
    finalize_kernel<<<LL, 256, 0, stream>>>(a_raw, b_raw, t1, out);
}